// Round 6
// baseline (274.913 us; speedup 1.0000x reference)
//
#include <hip/hip_runtime.h>
#include <math.h>

#define NG 16
#define DIM 64
#define LOG_2PI 1.8378770664093453f
#define RPW 4                      // rows per wave
#define WPB 4                      // waves per block (256 threads)
#define ROWS_PER_BLOCK (RPW * WPB) // 16

typedef float f32x4 __attribute__((ext_vector_type(4)));

// Round-6: round 5 (t/w prologue hoist) gained only ~2.5us -> steady state is
// no longer latency-bound. Remaining gap (72us vs 44us HBM floor) re-examined:
// round 3's NT loads forced ALL 268MB of means+covs to HBM every iteration,
// surrendering the 256MB LLC (round 2 proved cacheable reads got ~50% LLC
// service even while thrashing: FETCH 140MB vs 279MB compulsory).
// Fix: LLC partition. means (134MB) + targets (8MB) + weights (2MB) = 144MB
// -> CACHEABLE, near-resident in the 256MB LLC across iterations.
// covs (134MB) -> NT, streamed from HBM without evicting the resident set.
// HBM then moves ~134MB (~21us) while the LLC serves means in parallel.
//
// Mapping (verified, absmax=0): float4 f = lane + 64k of a row ->
// gaussian (lane>>4)+4k, dim-chunk lane&15 (same for all k). Butterfly
// 1/2/4/8 sums chunks; local 4-wide LSE; merge disjoint groups via xor 16/32.

#define NT(p) __builtin_nontemporal_load(p)

__global__ __launch_bounds__(256) void gmm_loss_kernel(
    const float* __restrict__ means,
    const float* __restrict__ covs,
    const float* __restrict__ weights,
    const float* __restrict__ targets,
    float* __restrict__ out, int B)
{
    const int lane = threadIdx.x & 63;
    const int wave = threadIdx.x >> 6;
    const int G = lane >> 4;     // lane group = base gaussian
    const int c = lane & 15;     // dim-chunk / weight index owned by this lane

    const int b0 = blockIdx.x * ROWS_PER_BLOCK + wave * RPW;

    // ---------- prologue: ALL rows' target chunks + weight scalars ----------
    const int rb0 = (b0 + 0) < B ? (b0 + 0) : (B - 1);
    const int rb1 = (b0 + 1) < B ? (b0 + 1) : (B - 1);
    const int rb2 = (b0 + 2) < B ? (b0 + 2) : (B - 1);
    const int rb3 = (b0 + 3) < B ? (b0 + 3) : (B - 1);
    const f32x4 tp0 = ((const f32x4*)(targets + (size_t)rb0 * DIM))[c];
    const f32x4 tp1 = ((const f32x4*)(targets + (size_t)rb1 * DIM))[c];
    const f32x4 tp2 = ((const f32x4*)(targets + (size_t)rb2 * DIM))[c];
    const f32x4 tp3 = ((const f32x4*)(targets + (size_t)rb3 * DIM))[c];
    const float wp0 = weights[(size_t)rb0 * NG + c];
    const float wp1 = weights[(size_t)rb1 * NG + c];
    const float wp2 = weights[(size_t)rb2 * NG + c];
    const float wp3 = weights[(size_t)rb3 * NG + c];

    // ---- issue row (bb)'s 8 big loads into buffer S ----
    // means: CACHEABLE (LLC-resident set). covs: NT (HBM stream, no pollute)
#define ISSUE(S, bb) {                                                        \
        const int rb = (bb) < B ? (bb) : (B - 1);                             \
        const f32x4* Mp = (const f32x4*)(means + (size_t)rb * (NG * DIM));    \
        const f32x4* Vp = (const f32x4*)(covs  + (size_t)rb * (NG * DIM));    \
        m0##S = Mp[lane];       v0##S = NT(Vp + lane);                        \
        m1##S = Mp[lane + 64];  v1##S = NT(Vp + lane + 64);                   \
        m2##S = Mp[lane + 128]; v2##S = NT(Vp + lane + 128);                  \
        m3##S = Mp[lane + 192]; v3##S = NT(Vp + lane + 192);                  \
    }

    // ---- consume buffer S for row (bb); t/w already in registers ----
#define COMPUTE(S, bb, t, wv) {                                               \
        float dx, p0, p1, p2, p3;                                             \
        dx = t.x - m0##S.x; p0  = dx * dx * __builtin_amdgcn_rcpf(v0##S.x);   \
        dx = t.y - m0##S.y; p0 += dx * dx * __builtin_amdgcn_rcpf(v0##S.y);   \
        dx = t.z - m0##S.z; p0 += dx * dx * __builtin_amdgcn_rcpf(v0##S.z);   \
        dx = t.w - m0##S.w; p0 += dx * dx * __builtin_amdgcn_rcpf(v0##S.w);   \
        p0 += __logf(v0##S.x * v0##S.y * v0##S.z * v0##S.w);                  \
        dx = t.x - m1##S.x; p1  = dx * dx * __builtin_amdgcn_rcpf(v1##S.x);   \
        dx = t.y - m1##S.y; p1 += dx * dx * __builtin_amdgcn_rcpf(v1##S.y);   \
        dx = t.z - m1##S.z; p1 += dx * dx * __builtin_amdgcn_rcpf(v1##S.z);   \
        dx = t.w - m1##S.w; p1 += dx * dx * __builtin_amdgcn_rcpf(v1##S.w);   \
        p1 += __logf(v1##S.x * v1##S.y * v1##S.z * v1##S.w);                  \
        dx = t.x - m2##S.x; p2  = dx * dx * __builtin_amdgcn_rcpf(v2##S.x);   \
        dx = t.y - m2##S.y; p2 += dx * dx * __builtin_amdgcn_rcpf(v2##S.y);   \
        dx = t.z - m2##S.z; p2 += dx * dx * __builtin_amdgcn_rcpf(v2##S.z);   \
        dx = t.w - m2##S.w; p2 += dx * dx * __builtin_amdgcn_rcpf(v2##S.w);   \
        p2 += __logf(v2##S.x * v2##S.y * v2##S.z * v2##S.w);                  \
        dx = t.x - m3##S.x; p3  = dx * dx * __builtin_amdgcn_rcpf(v3##S.x);   \
        dx = t.y - m3##S.y; p3 += dx * dx * __builtin_amdgcn_rcpf(v3##S.y);   \
        dx = t.z - m3##S.z; p3 += dx * dx * __builtin_amdgcn_rcpf(v3##S.z);   \
        dx = t.w - m3##S.w; p3 += dx * dx * __builtin_amdgcn_rcpf(v3##S.w);   \
        p3 += __logf(v3##S.x * v3##S.y * v3##S.z * v3##S.w);                  \
        p0 += __shfl_xor(p0, 1); p1 += __shfl_xor(p1, 1);                     \
        p2 += __shfl_xor(p2, 1); p3 += __shfl_xor(p3, 1);                     \
        p0 += __shfl_xor(p0, 2); p1 += __shfl_xor(p1, 2);                     \
        p2 += __shfl_xor(p2, 2); p3 += __shfl_xor(p3, 2);                     \
        p0 += __shfl_xor(p0, 4); p1 += __shfl_xor(p1, 4);                     \
        p2 += __shfl_xor(p2, 4); p3 += __shfl_xor(p3, 4);                     \
        p0 += __shfl_xor(p0, 8); p1 += __shfl_xor(p1, 8);                     \
        p2 += __shfl_xor(p2, 8); p3 += __shfl_xor(p3, 8);                     \
        const float lg = __logf(wv);                                          \
        const float lg0 = __shfl(lg, G);                                      \
        const float lg1 = __shfl(lg, G + 4);                                  \
        const float lg2 = __shfl(lg, G + 8);                                  \
        const float lg3 = __shfl(lg, G + 12);                                 \
        const float base = -0.5f * (DIM * LOG_2PI);                           \
        float lw0 = base - 0.5f * p0;                                         \
        float lw1 = base - 0.5f * p1;                                         \
        float lw2 = base - 0.5f * p2;                                         \
        float lw3 = base - 0.5f * p3;                                         \
        lw0 = fminf(fmaxf(lw0, -100.0f), 0.0f) + lg0;                         \
        lw1 = fminf(fmaxf(lw1, -100.0f), 0.0f) + lg1;                         \
        lw2 = fminf(fmaxf(lw2, -100.0f), 0.0f) + lg2;                         \
        lw3 = fminf(fmaxf(lw3, -100.0f), 0.0f) + lg3;                         \
        float M = fmaxf(fmaxf(lw0, lw1), fmaxf(lw2, lw3));                    \
        float s = __expf(lw0 - M) + __expf(lw1 - M) +                         \
                  __expf(lw2 - M) + __expf(lw3 - M);                          \
        {                                                                     \
            const float Mo = __shfl_xor(M, 16);                               \
            const float so = __shfl_xor(s, 16);                               \
            const float Mn = fmaxf(M, Mo);                                    \
            s = s * __expf(M - Mn) + so * __expf(Mo - Mn);                    \
            M = Mn;                                                           \
        }                                                                     \
        {                                                                     \
            const float Mo = __shfl_xor(M, 32);                               \
            const float so = __shfl_xor(s, 32);                               \
            const float Mn = fmaxf(M, Mo);                                    \
            s = s * __expf(M - Mn) + so * __expf(Mo - Mn);                    \
            M = Mn;                                                           \
        }                                                                     \
        if ((bb) < B && lane == 0) out[bb] = -(M + __logf(s));                \
    }

    f32x4 m0A, m1A, m2A, m3A, v0A, v1A, v2A, v3A;
    f32x4 m0B, m1B, m2B, m3B, v0B, v1B, v2B, v3B;

    // software pipeline: next row's m/v loads in flight through every compute;
    // t/w for all rows already resident from the prologue
    ISSUE(A, b0 + 0)
    ISSUE(B, b0 + 1)
    COMPUTE(A, b0 + 0, tp0, wp0)
    ISSUE(A, b0 + 2)
    COMPUTE(B, b0 + 1, tp1, wp1)
    ISSUE(B, b0 + 3)
    COMPUTE(A, b0 + 2, tp2, wp2)
    COMPUTE(B, b0 + 3, tp3, wp3)

#undef ISSUE
#undef COMPUTE
}

extern "C" void kernel_launch(void* const* d_in, const int* in_sizes, int n_in,
                              void* d_out, int out_size, void* d_ws, size_t ws_size,
                              hipStream_t stream) {
    const float* means   = (const float*)d_in[0];
    const float* covs    = (const float*)d_in[1];
    const float* weights = (const float*)d_in[2];
    const float* targets = (const float*)d_in[3];
    float* out = (float*)d_out;

    const int B = in_sizes[0] / (NG * DIM);                      // 32768
    const int grid = (B + ROWS_PER_BLOCK - 1) / ROWS_PER_BLOCK;  // 2048
    gmm_loss_kernel<<<grid, 256, 0, stream>>>(means, covs, weights, targets, out, B);
}

// Round 7
// 272.308 us; speedup vs baseline: 1.0096x; 1.0096x over previous
//
#include <hip/hip_runtime.h>
#include <math.h>

#define NG 16
#define DIM 64
#define LOG_2PI 1.8378770664093453f
#define RPW 4                      // rows per wave
#define WPB 4                      // waves per block (256 threads)
#define ROWS_PER_BLOCK (RPW * WPB) // 16

typedef float f32x4 __attribute__((ext_vector_type(4)));

// Round-7: round 6's LLC partition halved HBM traffic (FETCH 279->136MB,
// means/targets/weights LLC-served) but VGPR_Count=44 proved the compiler
// collapsed the software pipeline (two row-buffers alone need 64 VGPRs) --
// it sank the cacheable means loads back to their uses chasing occupancy,
// re-serializing each phase. Net: 72us -> 81us despite half the traffic.
// Fix: keep the traffic split, FORCE the pipeline through codegen:
//   (a) sched_barrier(0) after every ISSUE -> loads may not sink past it;
//   (b) __launch_bounds__(256,3) -> VGPR budget ~168/wave, removing the
//       allocator's incentive to sink loads for occupancy.
// Confirmation signal: VGPR_Count must jump to ~96-168.
//
// Mapping (verified, absmax=0): float4 f = lane + 64k of a row ->
// gaussian (lane>>4)+4k, dim-chunk lane&15 (same for all k). Butterfly
// 1/2/4/8 sums chunks; local 4-wide LSE; merge disjoint groups via xor 16/32.

#define NT(p) __builtin_nontemporal_load(p)
#define PIN() __builtin_amdgcn_sched_barrier(0)

__global__ __launch_bounds__(256, 3) void gmm_loss_kernel(
    const float* __restrict__ means,
    const float* __restrict__ covs,
    const float* __restrict__ weights,
    const float* __restrict__ targets,
    float* __restrict__ out, int B)
{
    const int lane = threadIdx.x & 63;
    const int wave = threadIdx.x >> 6;
    const int G = lane >> 4;     // lane group = base gaussian
    const int c = lane & 15;     // dim-chunk / weight index owned by this lane

    const int b0 = blockIdx.x * ROWS_PER_BLOCK + wave * RPW;

    // ---------- prologue: ALL rows' target chunks + weight scalars ----------
    const int rb0 = (b0 + 0) < B ? (b0 + 0) : (B - 1);
    const int rb1 = (b0 + 1) < B ? (b0 + 1) : (B - 1);
    const int rb2 = (b0 + 2) < B ? (b0 + 2) : (B - 1);
    const int rb3 = (b0 + 3) < B ? (b0 + 3) : (B - 1);
    const f32x4 tp0 = ((const f32x4*)(targets + (size_t)rb0 * DIM))[c];
    const f32x4 tp1 = ((const f32x4*)(targets + (size_t)rb1 * DIM))[c];
    const f32x4 tp2 = ((const f32x4*)(targets + (size_t)rb2 * DIM))[c];
    const f32x4 tp3 = ((const f32x4*)(targets + (size_t)rb3 * DIM))[c];
    const float wp0 = weights[(size_t)rb0 * NG + c];
    const float wp1 = weights[(size_t)rb1 * NG + c];
    const float wp2 = weights[(size_t)rb2 * NG + c];
    const float wp3 = weights[(size_t)rb3 * NG + c];

    // ---- issue row (bb)'s 8 big loads into buffer S ----
    // means: CACHEABLE (LLC-resident set). covs: NT (HBM stream, no pollute)
#define ISSUE(S, bb) {                                                        \
        const int rb = (bb) < B ? (bb) : (B - 1);                             \
        const f32x4* Mp = (const f32x4*)(means + (size_t)rb * (NG * DIM));    \
        const f32x4* Vp = (const f32x4*)(covs  + (size_t)rb * (NG * DIM));    \
        m0##S = Mp[lane];       v0##S = NT(Vp + lane);                        \
        m1##S = Mp[lane + 64];  v1##S = NT(Vp + lane + 64);                   \
        m2##S = Mp[lane + 128]; v2##S = NT(Vp + lane + 128);                  \
        m3##S = Mp[lane + 192]; v3##S = NT(Vp + lane + 192);                  \
    }

    // ---- consume buffer S for row (bb); t/w already in registers ----
#define COMPUTE(S, bb, t, wv) {                                               \
        float dx, p0, p1, p2, p3;                                             \
        dx = t.x - m0##S.x; p0  = dx * dx * __builtin_amdgcn_rcpf(v0##S.x);   \
        dx = t.y - m0##S.y; p0 += dx * dx * __builtin_amdgcn_rcpf(v0##S.y);   \
        dx = t.z - m0##S.z; p0 += dx * dx * __builtin_amdgcn_rcpf(v0##S.z);   \
        dx = t.w - m0##S.w; p0 += dx * dx * __builtin_amdgcn_rcpf(v0##S.w);   \
        p0 += __logf(v0##S.x * v0##S.y * v0##S.z * v0##S.w);                  \
        dx = t.x - m1##S.x; p1  = dx * dx * __builtin_amdgcn_rcpf(v1##S.x);   \
        dx = t.y - m1##S.y; p1 += dx * dx * __builtin_amdgcn_rcpf(v1##S.y);   \
        dx = t.z - m1##S.z; p1 += dx * dx * __builtin_amdgcn_rcpf(v1##S.z);   \
        dx = t.w - m1##S.w; p1 += dx * dx * __builtin_amdgcn_rcpf(v1##S.w);   \
        p1 += __logf(v1##S.x * v1##S.y * v1##S.z * v1##S.w);                  \
        dx = t.x - m2##S.x; p2  = dx * dx * __builtin_amdgcn_rcpf(v2##S.x);   \
        dx = t.y - m2##S.y; p2 += dx * dx * __builtin_amdgcn_rcpf(v2##S.y);   \
        dx = t.z - m2##S.z; p2 += dx * dx * __builtin_amdgcn_rcpf(v2##S.z);   \
        dx = t.w - m2##S.w; p2 += dx * dx * __builtin_amdgcn_rcpf(v2##S.w);   \
        p2 += __logf(v2##S.x * v2##S.y * v2##S.z * v2##S.w);                  \
        dx = t.x - m3##S.x; p3  = dx * dx * __builtin_amdgcn_rcpf(v3##S.x);   \
        dx = t.y - m3##S.y; p3 += dx * dx * __builtin_amdgcn_rcpf(v3##S.y);   \
        dx = t.z - m3##S.z; p3 += dx * dx * __builtin_amdgcn_rcpf(v3##S.z);   \
        dx = t.w - m3##S.w; p3 += dx * dx * __builtin_amdgcn_rcpf(v3##S.w);   \
        p3 += __logf(v3##S.x * v3##S.y * v3##S.z * v3##S.w);                  \
        p0 += __shfl_xor(p0, 1); p1 += __shfl_xor(p1, 1);                     \
        p2 += __shfl_xor(p2, 1); p3 += __shfl_xor(p3, 1);                     \
        p0 += __shfl_xor(p0, 2); p1 += __shfl_xor(p1, 2);                     \
        p2 += __shfl_xor(p2, 2); p3 += __shfl_xor(p3, 2);                     \
        p0 += __shfl_xor(p0, 4); p1 += __shfl_xor(p1, 4);                     \
        p2 += __shfl_xor(p2, 4); p3 += __shfl_xor(p3, 4);                     \
        p0 += __shfl_xor(p0, 8); p1 += __shfl_xor(p1, 8);                     \
        p2 += __shfl_xor(p2, 8); p3 += __shfl_xor(p3, 8);                     \
        const float lg = __logf(wv);                                          \
        const float lg0 = __shfl(lg, G);                                      \
        const float lg1 = __shfl(lg, G + 4);                                  \
        const float lg2 = __shfl(lg, G + 8);                                  \
        const float lg3 = __shfl(lg, G + 12);                                 \
        const float base = -0.5f * (DIM * LOG_2PI);                           \
        float lw0 = base - 0.5f * p0;                                         \
        float lw1 = base - 0.5f * p1;                                         \
        float lw2 = base - 0.5f * p2;                                         \
        float lw3 = base - 0.5f * p3;                                         \
        lw0 = fminf(fmaxf(lw0, -100.0f), 0.0f) + lg0;                         \
        lw1 = fminf(fmaxf(lw1, -100.0f), 0.0f) + lg1;                         \
        lw2 = fminf(fmaxf(lw2, -100.0f), 0.0f) + lg2;                         \
        lw3 = fminf(fmaxf(lw3, -100.0f), 0.0f) + lg3;                         \
        float M = fmaxf(fmaxf(lw0, lw1), fmaxf(lw2, lw3));                    \
        float s = __expf(lw0 - M) + __expf(lw1 - M) +                         \
                  __expf(lw2 - M) + __expf(lw3 - M);                          \
        {                                                                     \
            const float Mo = __shfl_xor(M, 16);                               \
            const float so = __shfl_xor(s, 16);                               \
            const float Mn = fmaxf(M, Mo);                                    \
            s = s * __expf(M - Mn) + so * __expf(Mo - Mn);                    \
            M = Mn;                                                           \
        }                                                                     \
        {                                                                     \
            const float Mo = __shfl_xor(M, 32);                               \
            const float so = __shfl_xor(s, 32);                               \
            const float Mn = fmaxf(M, Mo);                                    \
            s = s * __expf(M - Mn) + so * __expf(Mo - Mn);                    \
            M = Mn;                                                           \
        }                                                                     \
        if ((bb) < B && lane == 0) out[bb] = -(M + __logf(s));                \
    }

    f32x4 m0A, m1A, m2A, m3A, v0A, v1A, v2A, v3A;
    f32x4 m0B, m1B, m2B, m3B, v0B, v1B, v2B, v3B;

    // software pipeline: next row's m/v loads in flight through every compute.
    // sched_barrier(0) after each ISSUE pins the loads on the issue side of
    // the following COMPUTE -- the scheduler may not sink them.
    ISSUE(A, b0 + 0)
    PIN();
    ISSUE(B, b0 + 1)
    PIN();
    COMPUTE(A, b0 + 0, tp0, wp0)
    ISSUE(A, b0 + 2)
    PIN();
    COMPUTE(B, b0 + 1, tp1, wp1)
    ISSUE(B, b0 + 3)
    PIN();
    COMPUTE(A, b0 + 2, tp2, wp2)
    COMPUTE(B, b0 + 3, tp3, wp3)

#undef ISSUE
#undef COMPUTE
}

extern "C" void kernel_launch(void* const* d_in, const int* in_sizes, int n_in,
                              void* d_out, int out_size, void* d_ws, size_t ws_size,
                              hipStream_t stream) {
    const float* means   = (const float*)d_in[0];
    const float* covs    = (const float*)d_in[1];
    const float* weights = (const float*)d_in[2];
    const float* targets = (const float*)d_in[3];
    float* out = (float*)d_out;

    const int B = in_sizes[0] / (NG * DIM);                      // 32768
    const int grid = (B + ROWS_PER_BLOCK - 1) / ROWS_PER_BLOCK;  // 2048
    gmm_loss_kernel<<<grid, 256, 0, stream>>>(means, covs, weights, targets, out, B);
}